// Round 1
// baseline (498.295 us; speedup 1.0000x reference)
//
#include <hip/hip_runtime.h>
#include <hip/hip_bf16.h>

// Implicit-GEMM conv3x3 (stride 1, pad 1) + bias + residual + ReLU, NHWC.
// N=32, H=W=128, Cin=Cout=64, fp32 in/out, bf16 MFMA accumulation in fp32.
//
// Block = one output row (n, h): 128 pixels x 64 couts.
// 8 waves (512 thr) = 2 M-halves x 4 N-quarters. Wave computes 64 pix x 16 co
// = 4 MFMA tiles of 16x16, K = 576 (9 taps x 64 ci) in 18 steps of 32.
// Weights: 18 B-frags held in registers for the whole kernel (loaded once).
// x row staged to LDS as bf16 with XOR swizzle (G4 fix for 128B row stride).

typedef __bf16 bf16_t;
typedef __bf16 bf16x4 __attribute__((ext_vector_type(4)));
typedef __bf16 bf16x8 __attribute__((ext_vector_type(8)));
typedef float floatx4 __attribute__((ext_vector_type(4)));

#define H_ 128
#define W_ 128
#define CI_ 64
#define CO_ 64

__global__ __launch_bounds__(512, 2)
void conv3x3_fused(const float* __restrict__ x, const float* __restrict__ w,
                   const float* __restrict__ bias, const float* __restrict__ idn,
                   float* __restrict__ out)
{
    // 130 halo'd pixels x 64 ci, bf16, row stride 64 elem = 128 B.
    __shared__ bf16_t xs[130 * 64];

    const int tid  = threadIdx.x;
    const int lane = tid & 63;
    const int wid  = tid >> 6;   // 0..7
    const int wm   = wid >> 2;   // 0..1  M half (64 pixels)
    const int wn   = wid & 3;    // 0..3  N quarter (16 couts)
    const int l16  = lane & 15;
    const int lhi  = lane >> 4;  // 0..3

    const int bid = blockIdx.x;
    const int n = bid >> 7;
    const int h = bid & 127;

    const int co = wn * 16 + l16;

    // ---- weights -> registers: breg[j = kh*3+kw][kk], B[k=ci][n=co] frags ----
    // w layout: [co][kh][kw][ci] -> element w[co*576 + j*64 + kk*32 + k]
    bf16x8 breg[9][2];
    {
        const float* wp = w + co * 576;
        #pragma unroll
        for (int j = 0; j < 9; ++j) {
            #pragma unroll
            for (int kk = 0; kk < 2; ++kk) {
                const float* s = wp + j * 64 + kk * 32 + lhi * 8;
                floatx4 f0 = *reinterpret_cast<const floatx4*>(s);
                floatx4 f1 = *reinterpret_cast<const floatx4*>(s + 4);
                bf16x8 b;
                b[0] = (bf16_t)f0[0]; b[1] = (bf16_t)f0[1];
                b[2] = (bf16_t)f0[2]; b[3] = (bf16_t)f0[3];
                b[4] = (bf16_t)f1[0]; b[5] = (bf16_t)f1[1];
                b[6] = (bf16_t)f1[2]; b[7] = (bf16_t)f1[3];
                breg[j][kk] = b;
            }
        }
    }

    floatx4 acc[4];
    #pragma unroll
    for (int t = 0; t < 4; ++t) acc[t] = (floatx4){0.f, 0.f, 0.f, 0.f};

    const float* xplane = x + (size_t)n * (H_ * W_ * CI_);

    #pragma unroll
    for (int kh = 0; kh < 3; ++kh) {
        const int y = h + kh - 1;
        if (y < 0 || y >= H_) continue;   // uniform across block (zero padding)

        __syncthreads();  // previous kh's ds_reads done before overwriting xs

        // ---- stage row y: xs[p][ci] = x[n][y][p-1][ci], p in [0,130) ----
        {
            const float* srow = xplane + (size_t)y * (W_ * CI_);
            for (int g = tid; g < 130 * 16; g += 512) {
                const int p = g >> 4;        // halo'd pixel index
                const int c = g & 15;        // float4 chunk (4 ci)
                const int wpix = p - 1;
                floatx4 v = {0.f, 0.f, 0.f, 0.f};
                if (wpix >= 0 && wpix < W_)
                    v = *reinterpret_cast<const floatx4*>(srow + wpix * CI_ + c * 4);
                bf16x4 s4;
                s4[0] = (bf16_t)v[0]; s4[1] = (bf16_t)v[1];
                s4[2] = (bf16_t)v[2]; s4[3] = (bf16_t)v[3];
                const int idx = p * 64 + ((c * 4) ^ ((p & 7) << 3));  // XOR swizzle
                *reinterpret_cast<bf16x4*>(&xs[idx]) = s4;
            }
        }
        __syncthreads();

        // ---- MFMA: 3 kw x 2 ci-halves x 4 M-tiles ----
        #pragma unroll
        for (int kw = 0; kw < 3; ++kw) {
            const int j = kh * 3 + kw;
            #pragma unroll
            for (int kk = 0; kk < 2; ++kk) {
                #pragma unroll
                for (int mt = 0; mt < 4; ++mt) {
                    // A[m][k]: m = pixel (row l16), k = ci (lhi*8+e)
                    const int p  = wm * 64 + mt * 16 + l16 + kw;  // xs row (halo shift)
                    const int ci = kk * 32 + lhi * 8;
                    const int idx = p * 64 + (ci ^ ((p & 7) << 3));
                    bf16x8 a = *reinterpret_cast<const bf16x8*>(&xs[idx]);
                    acc[mt] = __builtin_amdgcn_mfma_f32_16x16x32_bf16(
                        a, breg[j][kk], acc[mt], 0, 0, 0);
                }
            }
        }
    }

    // ---- epilogue: bias + residual + ReLU, fp32 store ----
    // C/D layout: col(co) = lane&15, row(pixel) = (lane>>4)*4 + reg  [m89]
    const float bsc = bias[co];
    #pragma unroll
    for (int mt = 0; mt < 4; ++mt) {
        #pragma unroll
        for (int r = 0; r < 4; ++r) {
            const int wpos = wm * 64 + mt * 16 + lhi * 4 + r;
            const size_t gidx = (((size_t)(n * H_ + h)) * W_ + wpos) * CO_ + co;
            const float v = acc[mt][r] + bsc + idn[gidx];
            out[gidx] = fmaxf(v, 0.f);
        }
    }
}

extern "C" void kernel_launch(void* const* d_in, const int* in_sizes, int n_in,
                              void* d_out, int out_size, void* d_ws, size_t ws_size,
                              hipStream_t stream) {
    const float* x    = (const float*)d_in[0];
    const float* w    = (const float*)d_in[1];
    const float* bias = (const float*)d_in[2];
    const float* idn  = (const float*)d_in[3];
    float* out = (float*)d_out;

    dim3 grid(32 * 128);   // one block per (n, h) output row
    dim3 block(512);
    hipLaunchKernelGGL(conv3x3_fused, grid, block, 0, stream, x, w, bias, idn, out);
}

// Round 6
// 385.806 us; speedup vs baseline: 1.2916x; 1.2916x over previous
//
#include <hip/hip_runtime.h>
#include <hip/hip_bf16.h>

// Conv3x3 (stride1 pad1) + bias + residual + ReLU, NHWC, fp32 I/O.
// Two-kernel plan:
//  1) prep: x fp32 -> bf16 into ws with XOR-swizzled 16B-chunk order
//     (swizzle baked into global layout so global_load_lds dest stays linear),
//     w fp32 -> bf16, plus a 1KB zero pad region for halo lanes.
//  2) conv: async global_load_lds staging of 3 halo'd rows (ONE barrier),
//     weights in 18 reg B-frags, mfma_f32_16x16x32_bf16, fused epilogue.

typedef __bf16 bf16_t;
typedef __bf16 bf16x8 __attribute__((ext_vector_type(8)));
typedef __bf16 bf16x4 __attribute__((ext_vector_type(4)));
typedef float floatx4 __attribute__((ext_vector_type(4)));

#define H_ 128
#define W_ 128
#define CI_ 64
#define CO_ 64
#define NB_ 32

#define XCHUNKS (NB_ * H_ * W_ * 8)          // 16B chunks of x_bf16
#define WCHUNKS (CO_ * 576 / 8)              // 4608
#define X_BYTES ((size_t)XCHUNKS * 16)       // 67,108,864
#define W_OFF   X_BYTES
#define W_BYTES ((size_t)WCHUNKS * 16)       // 73,728
#define Z_OFF   (W_OFF + W_BYTES)
#define Z_BYTES 1024
#define WS_NEED (Z_OFF + Z_BYTES)

#define GLDS(src, dst)                                                        \
    __builtin_amdgcn_global_load_lds(                                         \
        (const __attribute__((address_space(1))) void*)(src),                 \
        (__attribute__((address_space(3))) void*)(dst), 16, 0, 0)

// ---------------------------------------------------------------- prep ----
__global__ __launch_bounds__(256)
void prep_bf16(const float* __restrict__ x, const float* __restrict__ w,
               char* __restrict__ ws)
{
    const int total = XCHUNKS + WCHUNKS + 64;
    bf16_t* xb = (bf16_t*)ws;
    bf16_t* wb = (bf16_t*)(ws + W_OFF);
    for (int t = blockIdx.x * blockDim.x + threadIdx.x; t < total;
         t += gridDim.x * blockDim.x) {
        if (t < XCHUNKS) {
            const int cs  = t & 7;            // stored 16B-slot within pixel row
            const int p   = (t >> 3) & 127;   // pixel (W)
            const int row = t >> 10;          // n*H + y
            const int c   = cs ^ (p & 7);     // original ci-chunk (involution)
            const float* s = x + ((size_t)row * 128 + p) * 64 + c * 8;
            floatx4 f0 = *(const floatx4*)s;
            floatx4 f1 = *(const floatx4*)(s + 4);
            bf16x8 b;
            b[0]=(bf16_t)f0[0]; b[1]=(bf16_t)f0[1]; b[2]=(bf16_t)f0[2]; b[3]=(bf16_t)f0[3];
            b[4]=(bf16_t)f1[0]; b[5]=(bf16_t)f1[1]; b[6]=(bf16_t)f1[2]; b[7]=(bf16_t)f1[3];
            *(bf16x8*)(xb + (size_t)t * 8) = b;
        } else if (t < XCHUNKS + WCHUNKS) {
            const int c = t - XCHUNKS;
            const float* s = w + (size_t)c * 8;
            floatx4 f0 = *(const floatx4*)s;
            floatx4 f1 = *(const floatx4*)(s + 4);
            bf16x8 b;
            b[0]=(bf16_t)f0[0]; b[1]=(bf16_t)f0[1]; b[2]=(bf16_t)f0[2]; b[3]=(bf16_t)f0[3];
            b[4]=(bf16_t)f1[0]; b[5]=(bf16_t)f1[1]; b[6]=(bf16_t)f1[2]; b[7]=(bf16_t)f1[3];
            *(bf16x8*)(wb + (size_t)c * 8) = b;
        } else {
            const int c = t - XCHUNKS - WCHUNKS;
            floatx4 z = {0.f, 0.f, 0.f, 0.f};
            *(floatx4*)(ws + Z_OFF + (size_t)c * 16) = z;
        }
    }
}

// ---------------------------------------------------------------- conv ----
// Block = one output row (n,h): 128 pixels x 64 couts. 8 waves = 2 wm x 4 wn.
// LDS: 3 halo'd rows, 136 pixels (130 + pad) x 64 ci bf16, swizzled chunks.
__global__ __launch_bounds__(512, 4)
void conv3x3_mfma(const char* __restrict__ ws, const float* __restrict__ bias,
                  const float* __restrict__ idn, float* __restrict__ out)
{
    __shared__ bf16_t xs[3 * 136 * 64];      // 52,224 B

    const int tid  = threadIdx.x;
    const int lane = tid & 63;
    const int wid  = tid >> 6;
    const int wm   = wid >> 2;    // 0..1
    const int wn   = wid & 3;     // 0..3
    const int l16  = lane & 15;
    const int lhi  = lane >> 4;   // 0..3

    // bijective XCD swizzle: contiguous (n,h) per XCD (4096 % 8 == 0)
    const int bid  = blockIdx.x;
    const int sbid = (bid & 7) * 512 + (bid >> 3);
    const int n = sbid >> 7;
    const int h = sbid & 127;

    const int co = wn * 16 + l16;

    const bf16_t* xb = (const bf16_t*)ws;
    const bf16_t* wb = (const bf16_t*)(ws + W_OFF);
    const char*   zb = ws + Z_OFF;

    // ---- async staging: 3 rows x 17 wave-instrs of 1KB, fire-and-forget ----
    {
        const int lsub = lane & 7;   // stored 16B slot
        const int lp   = lane >> 3;  // pixel within 8-pixel group
        #pragma unroll
        for (int r = 0; r < 3; ++r) {
            const int y = h + r - 1;
            if (y < 0 || y >= H_) continue;
            const char* rowbase =
                (const char*)(xb + ((size_t)(n * H_ + y) * 128) * 64);
            for (int s = wid; s < 17; s += 8) {
                const int ph = s * 8 + lp;       // halo'd pixel 0..135
                const int g  = ph - 1;           // global pixel
                const char* src = (g >= 0 && g < W_)
                                    ? rowbase + g * 128 + lsub * 16
                                    : zb + lane * 16;
                bf16_t* dst = &xs[(r * 136 + s * 8) * 64];
                GLDS(src, dst);
            }
        }
    }

    // ---- weights -> 18 register B-frags (L2-hot bf16) ----
    bf16x8 breg[9][2];
    {
        const bf16_t* wp = wb + (size_t)co * 576 + lhi * 8;
        #pragma unroll
        for (int j = 0; j < 9; ++j) {
            #pragma unroll
            for (int kk = 0; kk < 2; ++kk)
                breg[j][kk] = *(const bf16x8*)(wp + j * 64 + kk * 32);
        }
    }
    const float bsc = bias[co];

    __syncthreads();   // drains vmcnt (staging + breg)

    // ---- MFMA: 3 kh x 3 kw x 2 kk x 4 mt ----
    floatx4 acc[4];
    #pragma unroll
    for (int t = 0; t < 4; ++t) acc[t] = (floatx4){0.f, 0.f, 0.f, 0.f};

    const int px = wm * 64 + l16;
    int cbyte[3][2];
    #pragma unroll
    for (int kw = 0; kw < 3; ++kw) {
        const int key = (px + kw + 7) & 7;   // (global pixel)&7 = (p-1)&7
        #pragma unroll
        for (int kk = 0; kk < 2; ++kk)
            cbyte[kw][kk] = ((kk * 4 + lhi) ^ key) << 4;
    }

    #pragma unroll
    for (int r = 0; r < 3; ++r) {
        const int y = h + r - 1;
        if (y < 0 || y >= H_) continue;
        #pragma unroll
        for (int kw = 0; kw < 3; ++kw) {
            #pragma unroll
            for (int kk = 0; kk < 2; ++kk) {
                const int j = r * 3 + kw;
                #pragma unroll
                for (int mt = 0; mt < 4; ++mt) {
                    const int addr = (r * 136 + px + mt * 16 + kw) * 128
                                   + cbyte[kw][kk];
                    bf16x8 a = *(const bf16x8*)((const char*)xs + addr);
                    acc[mt] = __builtin_amdgcn_mfma_f32_16x16x32_bf16(
                        a, breg[j][kk], acc[mt], 0, 0, 0);
                }
            }
        }
    }

    // ---- epilogue: bias + residual + ReLU ----
    // C/D layout: col(co)=lane&15, row(pixel)=(lane>>4)*4 + reg
    #pragma unroll
    for (int mt = 0; mt < 4; ++mt) {
        float iv[4];
        #pragma unroll
        for (int rr = 0; rr < 4; ++rr) {
            const int wpos = wm * 64 + mt * 16 + lhi * 4 + rr;
            iv[rr] = idn[(((size_t)(n * H_ + h)) * W_ + wpos) * CO_ + co];
        }
        #pragma unroll
        for (int rr = 0; rr < 4; ++rr) {
            const int wpos = wm * 64 + mt * 16 + lhi * 4 + rr;
            const size_t gidx = (((size_t)(n * H_ + h)) * W_ + wpos) * CO_ + co;
            out[gidx] = fmaxf(acc[mt][rr] + bsc + iv[rr], 0.f);
        }
    }
}

// ---------------------------------------------- fallback (round-1 kernel) ----
__global__ __launch_bounds__(512, 2)
void conv3x3_fused_fb(const float* __restrict__ x, const float* __restrict__ w,
                      const float* __restrict__ bias, const float* __restrict__ idn,
                      float* __restrict__ out)
{
    __shared__ bf16_t xs[130 * 64];
    const int tid = threadIdx.x;
    const int lane = tid & 63;
    const int wid = tid >> 6;
    const int wm = wid >> 2, wn = wid & 3;
    const int l16 = lane & 15, lhi = lane >> 4;
    const int bid = blockIdx.x;
    const int n = bid >> 7, h = bid & 127;
    const int co = wn * 16 + l16;

    bf16x8 breg[9][2];
    {
        const float* wp = w + co * 576;
        #pragma unroll
        for (int j = 0; j < 9; ++j) {
            #pragma unroll
            for (int kk = 0; kk < 2; ++kk) {
                const float* s = wp + j * 64 + kk * 32 + lhi * 8;
                floatx4 f0 = *reinterpret_cast<const floatx4*>(s);
                floatx4 f1 = *reinterpret_cast<const floatx4*>(s + 4);
                bf16x8 b;
                b[0]=(bf16_t)f0[0]; b[1]=(bf16_t)f0[1]; b[2]=(bf16_t)f0[2]; b[3]=(bf16_t)f0[3];
                b[4]=(bf16_t)f1[0]; b[5]=(bf16_t)f1[1]; b[6]=(bf16_t)f1[2]; b[7]=(bf16_t)f1[3];
                breg[j][kk] = b;
            }
        }
    }
    floatx4 acc[4];
    #pragma unroll
    for (int t = 0; t < 4; ++t) acc[t] = (floatx4){0.f,0.f,0.f,0.f};
    const float* xplane = x + (size_t)n * (H_ * W_ * CI_);
    #pragma unroll
    for (int kh = 0; kh < 3; ++kh) {
        const int y = h + kh - 1;
        if (y < 0 || y >= H_) continue;
        __syncthreads();
        {
            const float* srow = xplane + (size_t)y * (W_ * CI_);
            for (int g = tid; g < 130 * 16; g += 512) {
                const int p = g >> 4, c = g & 15;
                const int wpix = p - 1;
                floatx4 v = {0.f,0.f,0.f,0.f};
                if (wpix >= 0 && wpix < W_)
                    v = *reinterpret_cast<const floatx4*>(srow + wpix * CI_ + c * 4);
                bf16x4 s4;
                s4[0]=(bf16_t)v[0]; s4[1]=(bf16_t)v[1]; s4[2]=(bf16_t)v[2]; s4[3]=(bf16_t)v[3];
                const int idx = p * 64 + ((c * 4) ^ ((p & 7) << 3));
                *reinterpret_cast<bf16x4*>(&xs[idx]) = s4;
            }
        }
        __syncthreads();
        #pragma unroll
        for (int kw = 0; kw < 3; ++kw) {
            const int j = kh * 3 + kw;
            #pragma unroll
            for (int kk = 0; kk < 2; ++kk) {
                #pragma unroll
                for (int mt = 0; mt < 4; ++mt) {
                    const int p = wm * 64 + mt * 16 + l16 + kw;
                    const int ci = kk * 32 + lhi * 8;
                    const int idx = p * 64 + (ci ^ ((p & 7) << 3));
                    bf16x8 a = *reinterpret_cast<const bf16x8*>(&xs[idx]);
                    acc[mt] = __builtin_amdgcn_mfma_f32_16x16x32_bf16(
                        a, breg[j][kk], acc[mt], 0, 0, 0);
                }
            }
        }
    }
    const float bsc = bias[co];
    #pragma unroll
    for (int mt = 0; mt < 4; ++mt) {
        #pragma unroll
        for (int rr = 0; rr < 4; ++rr) {
            const int wpos = wm * 64 + mt * 16 + lhi * 4 + rr;
            const size_t gidx = (((size_t)(n * H_ + h)) * W_ + wpos) * CO_ + co;
            out[gidx] = fmaxf(acc[mt][rr] + bsc + idn[gidx], 0.f);
        }
    }
}

extern "C" void kernel_launch(void* const* d_in, const int* in_sizes, int n_in,
                              void* d_out, int out_size, void* d_ws, size_t ws_size,
                              hipStream_t stream) {
    const float* x    = (const float*)d_in[0];
    const float* w    = (const float*)d_in[1];
    const float* bias = (const float*)d_in[2];
    const float* idn  = (const float*)d_in[3];
    float* out = (float*)d_out;

    if (ws_size >= WS_NEED) {
        hipLaunchKernelGGL(prep_bf16, dim3(2048), dim3(256), 0, stream,
                           x, w, (char*)d_ws);
        hipLaunchKernelGGL(conv3x3_mfma, dim3(4096), dim3(512), 0, stream,
                           (const char*)d_ws, bias, idn, out);
    } else {
        hipLaunchKernelGGL(conv3x3_fused_fb, dim3(4096), dim3(512), 0, stream,
                           x, w, bias, idn, out);
    }
}